// Round 3
// baseline (301.931 us; speedup 1.0000x reference)
//
#include <hip/hip_runtime.h>

typedef __attribute__((ext_vector_type(8))) short s16x8;            // 8 bf16 (MFMA A/B frag)
typedef __attribute__((ext_vector_type(4))) float f32x4;            // MFMA C/D frag

#define ALPHA_F 0.36787944117144233f
#define BETA_F  0.36787944117144233f
#define OMB_F   0.63212055882855767f   /* 1 - beta */

#define XS_STRIDE 40    /* 80B row: 16B-aligned b128 AND banks (20*l15+4q)%32 tile all 32 */
#define XS_ELEMS  (180*XS_STRIDE)      /* 7200 u16 = 14400 B per buffer */
#define YS_STRIDE 130   /* epilogue row pad: bank stride 65 dwords = odd -> <=2-way */

__device__ __forceinline__ unsigned short f2bf(float f){
  union { float f; unsigned int u; } v; v.f = f;
  unsigned int u = v.u;
  return (unsigned short)((u + 0x7FFFu + ((u >> 16) & 1u)) >> 16);  // RNE
}
__device__ __forceinline__ float bf2f(unsigned short s){
  union { unsigned int u; float f; } v; v.u = ((unsigned int)s) << 16;
  return v.f;
}

// ---- Kernel 0a: W (co,ci,3,3) fp32 -> Wr bf16 [pos9][cic4][co128][cil32] ----
__global__ __launch_bounds__(256) void reorder_w(const float* __restrict__ W,
                                                 unsigned short* __restrict__ Wr){
  int f = blockIdx.x * 256 + threadIdx.x;
  if (f >= 9*128*128) return;
  int cil = f & 31;
  int co  = (f >> 5) & 127;
  int cic = (f >> 12) & 3;
  int pos = f >> 14;
  int ci  = (cic << 5) | cil;
  Wr[f] = f2bf(W[(co*128 + ci)*9 + pos]);
}

// ---- Kernel 0b: x NCHW fp32 -> xcl channels-last bf16 [b][h][w][ci] ----
// One block per (b,h) row. Phase1: float4 reads, bf16-pair pack via shfl_xor +
// v_perm, dword LDS writes to [w][ci-pair] (stride 66 dwords). Phase2: b64 LDS
// reads (conflict-free), 8B coalesced global stores. Memory-bound by design.
__global__ __launch_bounds__(256) void x_to_cl(const float* __restrict__ x,
                                               unsigned short* __restrict__ xcl){
  __shared__ unsigned int ls32[112*66];       // [w][64 ci-pairs + 2 pad] = 29568 B
  const int tid = threadIdx.x;
  const int b = blockIdx.x / 112, h = blockIdx.x % 112;
  const float* xp = x + (size_t)b*1605632 + h*112;          // x[b][ci][h][w]
  const int lane = tid & 63, wid = tid >> 6;
  const int q = lane >> 1;              // float4 index along w, 0..31 (28 used)
  const int par = lane & 1;             // ci parity
  if (q < 28){
    #pragma unroll
    for (int i = 0; i < 16; ++i){
      int ci = (i << 3) + (wid << 1) + par;
      float4 v = *(const float4*)(xp + ci*12544 + (q << 2));
      unsigned int d01 = (unsigned int)f2bf(v.x) | ((unsigned int)f2bf(v.y) << 16);
      unsigned int d23 = (unsigned int)f2bf(v.z) | ((unsigned int)f2bf(v.w) << 16);
      unsigned int o01 = __shfl_xor(d01, 1);
      unsigned int o23 = __shfl_xor(d23, 1);
      unsigned int cs = par ? o23 : d01;   // even-ci dword for my w-pair
      unsigned int cv = par ? d23 : o01;   // odd-ci dword
      unsigned int outA = __builtin_amdgcn_perm(cv, cs, 0x05040100u); // w = wb
      unsigned int outB = __builtin_amdgcn_perm(cv, cs, 0x07060302u); // w = wb+1
      int wb = (q << 2) + (par << 1);
      int p  = (i << 2) + wid;             // ci-pair index, wave-uniform
      ls32[wb*66 + p]       = outA;
      ls32[(wb+1)*66 + p]   = outB;        // -> ds_write2_b32 offset1:66
    }
  }
  __syncthreads();
  unsigned short* op = xcl + (size_t)(b*112 + h) * (112*128);
  #pragma unroll
  for (int it = 0; it < 14; ++it){
    int idx = it*256 + tid;               // 112 pix * 32 groups
    int pix = idx >> 5, g = idx & 31;
    const unsigned int* lp = ls32 + pix*66 + (g << 1);
    uint2 d = *(const uint2*)lp;          // ds_read_b64, conflict-free
    *(uint2*)(op + (pix << 7) + (g << 2)) = d;   // 8B store, 512B/wave runs
  }
}

// ---- Kernel 1: fused implicit-GEMM conv3x3 (bf16 MFMA) + temporal IIR ----
// grid (7,14,16): bx=w-tile(16 cols), by=h-tile(8 rows), bz=batch.
// Block = 128 co x 128 pixels (8x16 patch). 4 waves, each 64co x 64pix.
// Double-buffered staging: prefetch chunk cic+1 into regs during cic compute.
__global__ __launch_bounds__(256, 3) void conv_lif(
    const unsigned short* __restrict__ xcl,
    const unsigned short* __restrict__ Wr,
    const float* __restrict__ bias,
    float* __restrict__ out)
{
  // xs double buffer: 2 x 180 pos x 40 u16 = 28800 B; epilogue aliases
  // ys[128 pix][130 u16] = 33280 B over the whole region.
  __shared__ unsigned short sm[128*YS_STRIDE];
  const int tid  = threadIdx.x;
  const int lane = tid & 63;
  const int wid  = tid >> 6;
  const int wm   = wid & 1;          // m-half (co 0..63 / 64..127)
  const int wn   = wid >> 1;         // n-half (rows 0..3 / 4..7)
  const int l15  = lane & 15;
  const int quad = lane >> 4;
  const int bz = blockIdx.z;
  const int h0 = blockIdx.y * 8, w0 = blockIdx.x * 16;

  f32x4 acc[4][4];
  #pragma unroll
  for (int i=0;i<4;i++)
    #pragma unroll
    for (int j=0;j<4;j++) acc[i][j] = (f32x4){0.f,0.f,0.f,0.f};

  const unsigned short* xb = xcl + (size_t)bz * (112*112*128);

  // per-thread staging units: u = tid + it*256, it<6 (1440 units of ushort4)
  int s_pos[6], s_valid[6];                // precomputed per-unit geometry
  const unsigned short* s_gp[6];
  #pragma unroll
  for (int it = 0; it < 6; ++it){
    int u = tid + it*256;
    int posidx = u >> 3, cq = u & 7;
    int r = posidx / 18, c = posidx - r*18;
    int gh = h0 - 1 + r, gw = w0 - 1 + c;
    s_valid[it] = (u < 1440) && (gh >= 0) && (gh < 112) && (gw >= 0) && (gw < 112);
    s_pos[it]   = posidx*XS_STRIDE + (cq << 2);
    s_gp[it]    = xb + (((gh*112 + gw) << 7) & 0x7FFFFFF) + (cq << 2);
  }

  ushort4 r4[6];
  #define LOADC(cic_) do{ int ci0 = (cic_) << 5; \
      _Pragma("unroll") \
      for (int it = 0; it < 6; ++it){ \
        ushort4 v = make_ushort4(0,0,0,0); \
        if (s_valid[it]) v = *(const ushort4*)(s_gp[it] + ci0); \
        r4[it] = v; } }while(0)
  #define WRITEC(buf_) do{ unsigned short* xw = sm + (buf_)*XS_ELEMS; \
      _Pragma("unroll") \
      for (int it = 0; it < 6; ++it){ \
        int u = tid + it*256; \
        if (u < 1440) *(ushort4*)(xw + s_pos[it]) = r4[it]; } }while(0)

  LOADC(0); WRITEC(0); LOADC(1);

  for (int cic = 0; cic < 4; ++cic){
    __syncthreads();                       // buf[cic&1] writes visible, prev reads done
    if (cic < 3){
      WRITEC((cic+1)&1);
      if (cic < 2) LOADC(cic+2);           // latency hidden under this cic's MFMAs
    }
    const unsigned short* xs = sm + (cic&1)*XS_ELEMS;
    #pragma unroll
    for (int pos = 0; pos < 9; ++pos){
      const int dh = pos/3, dw = pos - dh*3;
      // A-frags straight from L2-resident Wr: A[m=co][k=ci=quad*8+j]
      const unsigned short* wb = Wr + (((pos<<2) + cic) << 12) + (wm<<11)
                                    + (l15<<5) + (quad<<3);
      s16x8 af[4];
      #pragma unroll
      for (int mt=0; mt<4; ++mt)
        af[mt] = *(const s16x8*)(wb + (mt<<9));
      #pragma unroll
      for (int nt=0; nt<4; ++nt){
        int rr = (wn<<2) + nt;             // pixel row in 8x16 patch
        const unsigned short* bp = xs + ((rr+dh)*18 + (l15+dw))*XS_STRIDE + (quad<<3);
        s16x8 bfr = *(const s16x8*)bp;     // ds_read_b128, aligned + conflict-free
        #pragma unroll
        for (int mt=0; mt<4; ++mt)
          acc[mt][nt] = __builtin_amdgcn_mfma_f32_16x16x32_bf16(af[mt], bfr, acc[mt][nt], 0, 0, 0);
      }
    }
  }

  __syncthreads();                         // done with xs; alias as ys
  // C/D layout: col(n=pix)=lane&15, row(m=co)=quad*4+reg
  #pragma unroll
  for (int mt=0; mt<4; ++mt){
    int cobase = (wm<<6) + (mt<<4) + (quad<<2);
    float4 bv = *(const float4*)(bias + cobase);
    #pragma unroll
    for (int nt=0; nt<4; ++nt){
      int pix = (((wn<<2)+nt)<<4) + l15;
      f32x4 a = acc[mt][nt];
      ushort2 w01, w23;
      w01.x = f2bf(a.x + bv.x);
      w01.y = f2bf(a.y + bv.y);
      w23.x = f2bf(a.z + bv.z);
      w23.y = f2bf(a.w + bv.w);
      unsigned short* yp = sm + pix*YS_STRIDE + cobase;
      *(ushort2*)(yp)     = w01;
      *(ushort2*)(yp + 2) = w23;
    }
  }
  __syncthreads();

  // temporal IIR along t=co per pixel: s=alpha*s+y; m=beta*m+(1-beta)*s
  // 256 threads: half 1 warm-starts at t=48 (alpha^16 ~ 1e-7 << bf16 noise).
  {
    int pix  = tid & 127;
    int half = tid >> 7;
    int r = pix >> 4, c = pix & 15;
    float s = 0.f, m = 0.f;
    float* op = out + (size_t)bz*1605632 + (h0 + r)*112 + (w0 + c);
    const unsigned short* yr = sm + pix*YS_STRIDE;
    int t0    = half ? 48 : 0;
    int tstore= half ? 64 : 0;
    int tend  = half ? 128 : 64;
    for (int t = t0; t < tend; ++t){
      float y = bf2f(yr[t]);
      s = ALPHA_F * s + y;
      m = BETA_F  * m + OMB_F * s;
      if (t >= tstore) op[(size_t)t*12544] = m;   // coalesced along w in 64B runs
    }
  }
}

extern "C" void kernel_launch(void* const* d_in, const int* in_sizes, int n_in,
                              void* d_out, int out_size, void* d_ws, size_t ws_size,
                              hipStream_t stream){
  const float* x = (const float*)d_in[0];
  const float* W = (const float*)d_in[1];
  const float* b = (const float*)d_in[2];
  float* out = (float*)d_out;
  unsigned short* Wr  = (unsigned short*)d_ws;                       // 294912 B
  unsigned short* xcl = (unsigned short*)((char*)d_ws + (1 << 20));  // 51.4 MB
  reorder_w<<<576, 256, 0, stream>>>(W, Wr);
  x_to_cl<<<16*112, 256, 0, stream>>>(x, xcl);
  conv_lif<<<dim3(7, 14, 16), 256, 0, stream>>>(xcl, Wr, b, out);
}

// Round 4
// 265.398 us; speedup vs baseline: 1.1377x; 1.1377x over previous
//
#include <hip/hip_runtime.h>

typedef __attribute__((ext_vector_type(8))) short s16x8;            // 8 bf16 (MFMA A/B frag)
typedef __attribute__((ext_vector_type(8))) unsigned short u16x8;   // 16 B vector
typedef __attribute__((ext_vector_type(4))) float f32x4;            // MFMA C/D frag

#define ALPHA_F 0.36787944117144233f
#define BETA_F  0.36787944117144233f
#define OMB_F   0.63212055882855767f   /* 1 - beta */

#define XS_U16   5760   /* one staging buffer: 180 pos x 32 ci (u16) = 11520 B */
#define YS_STRIDE 130   /* epilogue row pad: bank stride 65 dwords (odd) */

__device__ __forceinline__ unsigned short f2bf(float f){
  union { float f; unsigned int u; } v; v.f = f;
  unsigned int u = v.u;
  return (unsigned short)((u + 0x7FFFu + ((u >> 16) & 1u)) >> 16);  // RNE
}
__device__ __forceinline__ float bf2f(unsigned short s){
  union { unsigned int u; float f; } v; v.u = ((unsigned int)s) << 16;
  return v.f;
}

// ---- Kernel 0: W (co,ci,3,3) fp32 -> Wr bf16 [pos9][cic4][co128][cil32] ----
__global__ __launch_bounds__(256) void reorder_w(const float* __restrict__ W,
                                                 unsigned short* __restrict__ Wr){
  int f = blockIdx.x * 256 + threadIdx.x;
  if (f >= 9*128*128) return;
  int cil = f & 31;
  int co  = (f >> 5) & 127;
  int cic = (f >> 12) & 3;
  int pos = f >> 14;
  int ci  = (cic << 5) | cil;
  Wr[f] = f2bf(W[(co*128 + ci)*9 + pos]);
}

// ---- Kernel 1: fully fused conv3x3 (bf16 MFMA, NCHW fp32 input) + IIR ----
// grid (7,14,16). Block = 128 co x 128 pixels (8x16 patch), 4 waves.
// Wave w computes co [32w,32w+32) x all 128 pixels: acc[2 mt][8 nt].
// Staging: in-kernel gather/transpose NCHW fp32 -> xs[pos][ci32] bf16, dbuf.
__global__ __launch_bounds__(256, 3) void conv_lif(
    const float* __restrict__ x,
    const unsigned short* __restrict__ Wr,
    const float* __restrict__ bias,
    float* __restrict__ out)
{
  // xs double buffer 2 x 11520 B; epilogue ys[128][130] aliases (33280 B)
  __shared__ unsigned short sm[128*YS_STRIDE];
  const int tid  = threadIdx.x;
  const int lane = tid & 63;
  const int wid  = tid >> 6;         // wave id = co block (32 co each)
  const int l15  = lane & 15;
  const int quad = lane >> 4;
  const int bz = blockIdx.z;
  const int h0 = blockIdx.y * 8, w0 = blockIdx.x * 16;

  const float* xb = x + (size_t)bz * 1605632;   // x[bz][ci][h][w]

  // ---- gather geometry: 720 units (pos 180 x cq 4), <=3 per thread ----
  int  g_off[3], g_ci0[3];
  bool g_val[3];
  #pragma unroll
  for (int it = 0; it < 3; ++it){
    int u = tid + it*256;
    bool act = (u < 720);
    int uu = act ? u : 0;
    int pos = uu >> 2, cq = uu & 3;
    int row = pos / 18, col = pos - row*18;
    int gh = h0 - 1 + row, gw = w0 - 1 + col;
    bool val = act && (gh >= 0) && (gh < 112) && (gw >= 0) && (gw < 112);
    g_off[it] = val ? (gh*112 + gw) : 0;
    g_ci0[it] = cq << 3;
    g_val[it] = val;
  }

  u16x8 g[3];
  #define GATHER(cic_) do{ \
    _Pragma("unroll") \
    for (int it = 0; it < 3; ++it){ \
      const float* p = xb + (size_t)(g_ci0[it] + ((cic_) << 5)) * 12544 + g_off[it]; \
      u16x8 v; \
      _Pragma("unroll") \
      for (int k = 0; k < 8; ++k){ \
        float f = p[(size_t)k * 12544]; \
        f = g_val[it] ? f : 0.0f; \
        v[k] = f2bf(f); \
      } \
      g[it] = v; \
    } }while(0)

  #define WBUF(buf_) do{ \
    unsigned short* xw = sm + (buf_)*XS_U16; \
    _Pragma("unroll") \
    for (int it = 0; it < 3; ++it){ \
      int u = tid + it*256; \
      if (u < 720) *(u16x8*)(xw + ((u >> 2) << 5) + ((u & 3) << 3)) = g[it]; \
    } }while(0)

  f32x4 acc[2][8];
  #pragma unroll
  for (int i = 0; i < 2; ++i)
    #pragma unroll
    for (int j = 0; j < 8; ++j) acc[i][j] = (f32x4){0.f,0.f,0.f,0.f};

  GATHER(0); WBUF(0);

  for (int cic = 0; cic < 4; ++cic){
    __syncthreads();                        // xs[cic&1] visible; prev readers done
    const unsigned short* xs = sm + (cic & 1)*XS_U16;
    #pragma unroll
    for (int dw = 0; dw < 3; ++dw){
      // A-frags (L2-resident Wr): af[dh][mt], co = wid*32 + mt*16 + l15
      s16x8 af[3][2];
      #pragma unroll
      for (int dh = 0; dh < 3; ++dh){
        const unsigned short* wp = Wr + ((((dh*3 + dw) << 2) + cic) << 12)
                                      + (((wid << 5) + l15) << 5) + (quad << 3);
        af[dh][0] = *(const s16x8*)wp;
        af[dh][1] = *(const s16x8*)(wp + 512);
      }
      // B rows: ring of 6, rows r = nt+dh in [0,10); col = l15+dw, ci = quad*8+
      const unsigned short* bcol = xs + ((l15 + dw) << 5) + (quad << 3);
      s16x8 R[6];
      #pragma unroll
      for (int r = 0; r < 4; ++r) R[r] = *(const s16x8*)(bcol + r*576);
      #pragma unroll
      for (int p = 0; p < 4; ++p){
        if (p < 3){
          R[(2*p+4) % 6] = *(const s16x8*)(bcol + (2*p+4)*576);
          R[(2*p+5) % 6] = *(const s16x8*)(bcol + (2*p+5)*576);
        }
        #pragma unroll
        for (int dh = 0; dh < 3; ++dh){
          #pragma unroll
          for (int sub = 0; sub < 2; ++sub){
            int nt = 2*p + sub;
            s16x8 b = R[(nt + dh) % 6];
            acc[0][nt] = __builtin_amdgcn_mfma_f32_16x16x32_bf16(af[dh][0], b, acc[0][nt], 0, 0, 0);
            acc[1][nt] = __builtin_amdgcn_mfma_f32_16x16x32_bf16(af[dh][1], b, acc[1][nt], 0, 0, 0);
          }
        }
      }
      // issue next chunk's gathers after dw=1: dw=2's A-loads are already in
      // flight (vmcnt order), and dw=2's ~930 MFMA cycles hide gather latency.
      if (dw == 1 && cic < 3) GATHER(cic+1);
    }
    if (cic < 3) WBUF((cic+1) & 1);         // pack waits on gathers here
  }

  __syncthreads();                          // done with xs; alias as ys
  // C/D layout: col(n=pix)=lane&15, row(m)=quad*4+reg; co = wid*32+mt*16+m
  #pragma unroll
  for (int mt = 0; mt < 2; ++mt){
    int cobase = (wid << 5) + (mt << 4) + (quad << 2);
    float4 bv = *(const float4*)(bias + cobase);
    #pragma unroll
    for (int nt = 0; nt < 8; ++nt){
      int pix = (nt << 4) + l15;
      f32x4 a = acc[mt][nt];
      ushort2 w01, w23;
      w01.x = f2bf(a.x + bv.x);
      w01.y = f2bf(a.y + bv.y);
      w23.x = f2bf(a.z + bv.z);
      w23.y = f2bf(a.w + bv.w);
      unsigned short* yp = sm + pix*YS_STRIDE + cobase;
      *(ushort2*)(yp)     = w01;
      *(ushort2*)(yp + 2) = w23;
    }
  }
  __syncthreads();

  // temporal IIR along t=co per pixel: s=alpha*s+y; m=beta*m+(1-beta)*s
  // half 1 warm-starts at t=48 (alpha^16 ~ 1e-7 << bf16 noise).
  {
    int pix  = tid & 127;
    int half = tid >> 7;
    int r = pix >> 4, c = pix & 15;
    float s = 0.f, m = 0.f;
    float* op = out + (size_t)bz*1605632 + (h0 + r)*112 + (w0 + c);
    const unsigned short* yr = sm + pix*YS_STRIDE;
    int t0     = half ? 48 : 0;
    int tstore = half ? 64 : 0;
    int tend   = half ? 128 : 64;
    for (int t = t0; t < tend; ++t){
      float y = bf2f(yr[t]);
      s = ALPHA_F * s + y;
      m = BETA_F  * m + OMB_F * s;
      if (t >= tstore) op[(size_t)t*12544] = m;   // 64 B runs along w
    }
  }
  #undef GATHER
  #undef WBUF
}

extern "C" void kernel_launch(void* const* d_in, const int* in_sizes, int n_in,
                              void* d_out, int out_size, void* d_ws, size_t ws_size,
                              hipStream_t stream){
  const float* x = (const float*)d_in[0];
  const float* W = (const float*)d_in[1];
  const float* b = (const float*)d_in[2];
  float* out = (float*)d_out;
  unsigned short* Wr = (unsigned short*)d_ws;    // 294912 B
  reorder_w<<<576, 256, 0, stream>>>(W, Wr);
  conv_lif<<<dim3(7, 14, 16), 256, 0, stream>>>(x, Wr, b, out);
}